// Round 7
// baseline (366.262 us; speedup 1.0000x reference)
//
#include <hip/hip_runtime.h>

#define N_NODES 50000
#define N_EDGES 800000
#define IN_CH 128
#define HID 64
#define HID2 32
#define BN_EPS 1e-5f

// ---------- degree + per-edge rank (one atomic pass, coalesced rank store) ----------
__global__ __launch_bounds__(256) void k_degrank(const int* __restrict__ ei, int* __restrict__ deg,
                                                 int* __restrict__ rank, int E) {
    int t = blockIdx.x * 256 + threadIdx.x;
    int e = t * 4;
    if (e >= E) return;
    int4 c4 = *(const int4*)(ei + E + e);
    int4 rk;
    rk.x = atomicAdd(&deg[c4.x], 1);
    rk.y = atomicAdd(&deg[c4.y], 1);
    rk.z = atomicAdd(&deg[c4.z], 1);
    rk.w = atomicAdd(&deg[c4.w], 1);
    *(int4*)(rank + e) = rk;
}

// ---------- scan stage 1: block sums + dinv + degree histogram ----------
__global__ __launch_bounds__(256) void k_scan1(const int* __restrict__ deg, int* __restrict__ bsum,
                                               float* __restrict__ dinv, int* __restrict__ dhist, int N) {
    __shared__ int s[256];
    __shared__ int hist[256];
    int i = blockIdx.x * 256 + threadIdx.x, t = threadIdx.x;
    int d = (i < N) ? deg[i] : 0;
    if (i < N) dinv[i] = rsqrtf((float)d + 1.0f);  // +1 = self loop
    hist[t] = 0;
    s[t] = d;
    __syncthreads();
    if (i < N) atomicAdd(&hist[d < 255 ? d : 255], 1);
    for (int off = 128; off > 0; off >>= 1) {
        if (t < off) s[t] += s[t + off];
        __syncthreads();
    }
    if (t == 0) bsum[blockIdx.x] = s[0];
    if (hist[t] > 0) atomicAdd(&dhist[t], hist[t]);
}

// ---------- scan stage 2 (single block): scan block sums AND degree bins ----------
__global__ __launch_bounds__(256) void k_scan2(const int* __restrict__ bsum, int* __restrict__ bofs,
                                               int* __restrict__ offs, const int* __restrict__ dhist,
                                               int* __restrict__ dcur, int NB, int N) {
    __shared__ int s[256];
    int t = threadIdx.x;
    int v = (t < NB) ? bsum[t] : 0;
    s[t] = v; __syncthreads();
    for (int off = 1; off < 256; off <<= 1) {
        int u = (t >= off) ? s[t - off] : 0;
        __syncthreads(); s[t] += u; __syncthreads();
    }
    if (t < NB) bofs[t] = s[t] - v;          // exclusive
    if (t == NB - 1) offs[N] = s[t];         // total == E
    __syncthreads();
    int h = dhist[t];
    s[t] = h; __syncthreads();
    for (int off = 1; off < 256; off <<= 1) {
        int u = (t >= off) ? s[t - off] : 0;
        __syncthreads(); s[t] += u; __syncthreads();
    }
    dcur[t] = s[t] - h;                      // exclusive bin start = cursor init
}

// ---------- scan stage 3: node offsets + degree-sorted permutation ----------
__global__ __launch_bounds__(256) void k_scan3(const int* __restrict__ deg, const int* __restrict__ bofs,
                                               int* __restrict__ offs, int* __restrict__ dcur,
                                               int* __restrict__ perm, int N) {
    __shared__ int s[256];
    int i = blockIdx.x * 256 + threadIdx.x, t = threadIdx.x;
    int v = (i < N) ? deg[i] : 0;
    s[t] = v; __syncthreads();
    for (int off = 1; off < 256; off <<= 1) {
        int u = (t >= off) ? s[t - off] : 0;
        __syncthreads(); s[t] += u; __syncthreads();
    }
    if (i < N) {
        offs[i] = bofs[blockIdx.x] + s[t] - v;
        int pos = atomicAdd(&dcur[v < 255 ? v : 255], 1);
        perm[pos] = i;
    }
}

// ---------- CSR fill, atomic-free: csr[offs[c]+rank[e]] = row (ushort: N<65536) ----------
__global__ __launch_bounds__(256) void k_fillr(const int* __restrict__ ei, const int* __restrict__ rank,
                                               const int* __restrict__ offs, unsigned short* __restrict__ csr, int E) {
    int t = blockIdx.x * 256 + threadIdx.x;
    int e = t * 4;
    if (e >= E) return;
    int4 r4 = *(const int4*)(ei + e);
    int4 c4 = *(const int4*)(ei + E + e);
    int4 k4 = *(const int4*)(rank + e);
    csr[offs[c4.x] + k4.x] = (unsigned short)r4.x;
    csr[offs[c4.y] + k4.y] = (unsigned short)r4.y;
    csr[offs[c4.z] + k4.z] = (unsigned short)r4.z;
    csr[offs[c4.w] + k4.w] = (unsigned short)r4.w;
}

// ---------- LDS-tiled GEMM: outp[n][f] = dinv[n] * sum_k in[n][k]*W[k][f] ----------
template <int BM, int KD, int FD, int AS>
__global__ __launch_bounds__(256) void k_gemm(const float* __restrict__ in, const float* __restrict__ W,
                                              const float* __restrict__ dinv, float* __restrict__ outp, int N) {
    __shared__ float As[BM * AS];
    __shared__ float Ws[KD * FD];
    int tid = threadIdx.x;
    int n0 = blockIdx.x * BM;
    const int TOT4 = BM * KD / 4;
    const int K4 = KD / 4;
#pragma unroll
    for (int idx = tid; idx < TOT4; idx += 256) {
        int r = idx / K4, c = idx % K4;
        int n = n0 + r; if (n > N - 1) n = N - 1;
        float4 v = *(const float4*)(in + (size_t)n * KD + c * 4);
        *(float4*)(As + r * AS + c * 4) = v;
    }
    const int WT4 = KD * FD / 4;
#pragma unroll
    for (int idx = tid; idx < WT4; idx += 256) {
        *(float4*)(Ws + idx * 4) = *(const float4*)(W + idx * 4);
    }
    __syncthreads();
    const int NFG = FD / 4;
    int tn = tid % NFG, tm = tid / NFG;
    int na = tm * 4, fb = tn * 4;
    float acc[4][4] = {};
#pragma unroll 4
    for (int k = 0; k < KD; k += 4) {
        float4 a[4], b[4];
#pragma unroll
        for (int i = 0; i < 4; ++i) a[i] = *(const float4*)(As + (na + i) * AS + k);
#pragma unroll
        for (int j = 0; j < 4; ++j) b[j] = *(const float4*)(Ws + (k + j) * FD + fb);
#pragma unroll
        for (int i = 0; i < 4; ++i) {
            acc[i][0] = fmaf(a[i].x, b[0].x, acc[i][0]);
            acc[i][1] = fmaf(a[i].x, b[0].y, acc[i][1]);
            acc[i][2] = fmaf(a[i].x, b[0].z, acc[i][2]);
            acc[i][3] = fmaf(a[i].x, b[0].w, acc[i][3]);
            acc[i][0] = fmaf(a[i].y, b[1].x, acc[i][0]);
            acc[i][1] = fmaf(a[i].y, b[1].y, acc[i][1]);
            acc[i][2] = fmaf(a[i].y, b[1].z, acc[i][2]);
            acc[i][3] = fmaf(a[i].y, b[1].w, acc[i][3]);
            acc[i][0] = fmaf(a[i].z, b[2].x, acc[i][0]);
            acc[i][1] = fmaf(a[i].z, b[2].y, acc[i][1]);
            acc[i][2] = fmaf(a[i].z, b[2].z, acc[i][2]);
            acc[i][3] = fmaf(a[i].z, b[2].w, acc[i][3]);
            acc[i][0] = fmaf(a[i].w, b[3].x, acc[i][0]);
            acc[i][1] = fmaf(a[i].w, b[3].y, acc[i][1]);
            acc[i][2] = fmaf(a[i].w, b[3].z, acc[i][2]);
            acc[i][3] = fmaf(a[i].w, b[3].w, acc[i][3]);
        }
    }
#pragma unroll
    for (int i = 0; i < 4; ++i) {
        int n = n0 + na + i;
        if (n < N) {
            float dn = dinv[n];
            float4 o = make_float4(acc[i][0] * dn, acc[i][1] * dn, acc[i][2] * dn, acc[i][3] * dn);
            *(float4*)(outp + (size_t)n * FD + fb) = o;
        }
    }
}

// ---------- gather layer 1: 4 nodes/wave via degree-sorted perm, lane = 4 feats ----------
__global__ __launch_bounds__(256) void k_gather1(const float* __restrict__ h1p, const int* __restrict__ offs,
                                                 const unsigned short* __restrict__ csr, const float* __restrict__ dinv,
                                                 const int* __restrict__ perm,
                                                 const float* __restrict__ b1, const float* __restrict__ g1,
                                                 const float* __restrict__ be1, const float* __restrict__ rm1,
                                                 const float* __restrict__ rv1, float* __restrict__ hact, int N) {
    int wid = (blockIdx.x * 256 + threadIdx.x) >> 6;
    int lane = threadIdx.x & 63;
    int sub = lane >> 4;              // node slot 0..3
    int l16 = lane & 15;
    int fl = l16 << 2;                // feature base
    int pidx = wid * 4 + sub;
    if (pidx > N - 1) pidx = N - 1;   // duplicate work, benign (same value rewritten)
    int nd = perm[pidx];
    int start = offs[nd], end = offs[nd + 1];
    float4 acc = *(const float4*)(h1p + ((size_t)nd << 6) + fl);   // self loop
    int sb = sub << 4;
    for (int j = start; j < end; j += 16) {
        int rid = (j + l16 < end) ? (int)csr[j + l16] : 0;
        int cnt = end - j; if (cnt > 16) cnt = 16;
        int t = 0;
        for (; t + 7 < cnt; t += 8) {
            int r0 = __shfl(rid, sb + t + 0, 64), r1 = __shfl(rid, sb + t + 1, 64);
            int r2 = __shfl(rid, sb + t + 2, 64), r3 = __shfl(rid, sb + t + 3, 64);
            int r4 = __shfl(rid, sb + t + 4, 64), r5 = __shfl(rid, sb + t + 5, 64);
            int r6 = __shfl(rid, sb + t + 6, 64), r7 = __shfl(rid, sb + t + 7, 64);
            float4 v0 = *(const float4*)(h1p + ((size_t)r0 << 6) + fl);
            float4 v1 = *(const float4*)(h1p + ((size_t)r1 << 6) + fl);
            float4 v2 = *(const float4*)(h1p + ((size_t)r2 << 6) + fl);
            float4 v3 = *(const float4*)(h1p + ((size_t)r3 << 6) + fl);
            float4 v4 = *(const float4*)(h1p + ((size_t)r4 << 6) + fl);
            float4 v5 = *(const float4*)(h1p + ((size_t)r5 << 6) + fl);
            float4 v6 = *(const float4*)(h1p + ((size_t)r6 << 6) + fl);
            float4 v7 = *(const float4*)(h1p + ((size_t)r7 << 6) + fl);
            acc.x += ((v0.x + v1.x) + (v2.x + v3.x)) + ((v4.x + v5.x) + (v6.x + v7.x));
            acc.y += ((v0.y + v1.y) + (v2.y + v3.y)) + ((v4.y + v5.y) + (v6.y + v7.y));
            acc.z += ((v0.z + v1.z) + (v2.z + v3.z)) + ((v4.z + v5.z) + (v6.z + v7.z));
            acc.w += ((v0.w + v1.w) + (v2.w + v3.w)) + ((v4.w + v5.w) + (v6.w + v7.w));
        }
        for (; t < cnt; ++t) {
            int r = __shfl(rid, sb + t, 64);
            float4 v = *(const float4*)(h1p + ((size_t)r << 6) + fl);
            acc.x += v.x; acc.y += v.y; acc.z += v.z; acc.w += v.w;
        }
    }
    float dn = dinv[nd];
    float4 bb = *(const float4*)(b1 + fl);
    float4 gg = *(const float4*)(g1 + fl);
    float4 ee = *(const float4*)(be1 + fl);
    float4 mm = *(const float4*)(rm1 + fl);
    float4 vv = *(const float4*)(rv1 + fl);
    float4 o;
    o.x = fmaxf((dn * acc.x + bb.x - mm.x) * (gg.x * rsqrtf(vv.x + BN_EPS)) + ee.x, 0.f);
    o.y = fmaxf((dn * acc.y + bb.y - mm.y) * (gg.y * rsqrtf(vv.y + BN_EPS)) + ee.y, 0.f);
    o.z = fmaxf((dn * acc.z + bb.z - mm.z) * (gg.z * rsqrtf(vv.z + BN_EPS)) + ee.z, 0.f);
    o.w = fmaxf((dn * acc.w + bb.w - mm.w) * (gg.w * rsqrtf(vv.w + BN_EPS)) + ee.w, 0.f);
    *(float4*)(hact + ((size_t)nd << 6) + fl) = o;
}

// ---------- gather layer 2: 8 nodes/wave via perm, lane = 4 feats + fused FC ----------
__global__ __launch_bounds__(256) void k_gather2(const float* __restrict__ h2p, const int* __restrict__ offs,
                                                 const unsigned short* __restrict__ csr, const float* __restrict__ dinv,
                                                 const int* __restrict__ perm,
                                                 const float* __restrict__ b2, const float* __restrict__ g2,
                                                 const float* __restrict__ be2, const float* __restrict__ rm2,
                                                 const float* __restrict__ rv2, const float* __restrict__ fcW,
                                                 const float* __restrict__ fcb, float* __restrict__ out, int N) {
    int wid = (blockIdx.x * 256 + threadIdx.x) >> 6;
    int lane = threadIdx.x & 63;
    int sub = lane >> 3;              // node slot 0..7
    int l8 = lane & 7;
    int fl = l8 << 2;                 // feature base 0..28
    int pidx = wid * 8 + sub;
    if (pidx > N - 1) pidx = N - 1;
    int nd = perm[pidx];
    int start = offs[nd], end = offs[nd + 1];
    float4 acc = *(const float4*)(h2p + ((size_t)nd << 5) + fl);   // self loop
    int sb = sub << 3;
    for (int j = start; j < end; j += 8) {
        int rid = (j + l8 < end) ? (int)csr[j + l8] : 0;
        int cnt = end - j; if (cnt > 8) cnt = 8;
        int t = 0;
        for (; t + 3 < cnt; t += 4) {
            int r0 = __shfl(rid, sb + t + 0, 64), r1 = __shfl(rid, sb + t + 1, 64);
            int r2 = __shfl(rid, sb + t + 2, 64), r3 = __shfl(rid, sb + t + 3, 64);
            float4 v0 = *(const float4*)(h2p + ((size_t)r0 << 5) + fl);
            float4 v1 = *(const float4*)(h2p + ((size_t)r1 << 5) + fl);
            float4 v2 = *(const float4*)(h2p + ((size_t)r2 << 5) + fl);
            float4 v3 = *(const float4*)(h2p + ((size_t)r3 << 5) + fl);
            acc.x += (v0.x + v1.x) + (v2.x + v3.x);
            acc.y += (v0.y + v1.y) + (v2.y + v3.y);
            acc.z += (v0.z + v1.z) + (v2.z + v3.z);
            acc.w += (v0.w + v1.w) + (v2.w + v3.w);
        }
        for (; t < cnt; ++t) {
            int r = __shfl(rid, sb + t, 64);
            float4 v = *(const float4*)(h2p + ((size_t)r << 5) + fl);
            acc.x += v.x; acc.y += v.y; acc.z += v.z; acc.w += v.w;
        }
    }
    float dn = dinv[nd];
    float4 bb = *(const float4*)(b2 + fl);
    float4 gg = *(const float4*)(g2 + fl);
    float4 ee = *(const float4*)(be2 + fl);
    float4 mm = *(const float4*)(rm2 + fl);
    float4 vv = *(const float4*)(rv2 + fl);
    float4 ww = *(const float4*)(fcW + fl);
    float s;
    s  = fmaxf((dn * acc.x + bb.x - mm.x) * (gg.x * rsqrtf(vv.x + BN_EPS)) + ee.x, 0.f) * ww.x;
    s += fmaxf((dn * acc.y + bb.y - mm.y) * (gg.y * rsqrtf(vv.y + BN_EPS)) + ee.y, 0.f) * ww.y;
    s += fmaxf((dn * acc.z + bb.z - mm.z) * (gg.z * rsqrtf(vv.z + BN_EPS)) + ee.z, 0.f) * ww.z;
    s += fmaxf((dn * acc.w + bb.w - mm.w) * (gg.w * rsqrtf(vv.w + BN_EPS)) + ee.w, 0.f) * ww.w;
    s += __shfl_down(s, 4, 8);
    s += __shfl_down(s, 2, 8);
    s += __shfl_down(s, 1, 8);
    if (l8 == 0) out[nd] = s + fcb[0];
}

extern "C" void kernel_launch(void* const* d_in, const int* in_sizes, int n_in,
                              void* d_out, int out_size, void* d_ws, size_t ws_size,
                              hipStream_t stream) {
    const float* x   = (const float*)d_in[0];
    const int*   ei  = (const int*)d_in[1];
    const float* W1  = (const float*)d_in[2];
    const float* b1  = (const float*)d_in[3];
    const float* W2  = (const float*)d_in[4];
    const float* b2  = (const float*)d_in[5];
    const float* fcW = (const float*)d_in[6];
    const float* fcb = (const float*)d_in[7];
    const float* g1  = (const float*)d_in[8];
    const float* be1 = (const float*)d_in[9];
    const float* rm1 = (const float*)d_in[10];
    const float* rv1 = (const float*)d_in[11];
    const float* g2  = (const float*)d_in[12];
    const float* be2 = (const float*)d_in[13];
    const float* rm2 = (const float*)d_in[14];
    const float* rv2 = (const float*)d_in[15];
    float* out = (float*)d_out;

    const int N = N_NODES, E = N_EDGES;
    const int NB = (N + 255) / 256;          // 196 scan blocks

    char* base = (char*)d_ws;
    int*            deg  = (int*)(base);                      // N ints
    int*            offs = (int*)(base + 200704);             // N+1 ints
    float*          dinv = (float*)(base + 401408);           // N floats
    int*            perm = (int*)(base + 602112);             // N ints
    int*            bsum = (int*)(base + 802816);             // 256
    int*            bofs = (int*)(base + 803840);             // 256
    int*            dhist= (int*)(base + 804864);             // 256
    int*            dcur = (int*)(base + 805888);             // 256
    int*            rank = (int*)(base + 806912);             // E ints (3.2 MB)
    unsigned short* csr  = (unsigned short*)(base + 4006912); // E ushort (1.6 MB)
    float*          h1p  = (float*)(base + 5606912);          // N*64 (12.8 MB)
    float*          hact = (float*)(base + 18406912);         // N*64 (12.8 MB)
    float*          h2p  = h1p;   // h1p dead after gather1

    hipMemsetAsync(deg, 0, (size_t)N * sizeof(int), stream);
    hipMemsetAsync(dhist, 0, 256 * sizeof(int), stream);

    k_degrank<<<(E / 4 + 255) / 256, 256, 0, stream>>>(ei, deg, rank, E);
    k_scan1<<<NB, 256, 0, stream>>>(deg, bsum, dinv, dhist, N);
    k_scan2<<<1, 256, 0, stream>>>(bsum, bofs, offs, dhist, dcur, NB, N);
    k_scan3<<<NB, 256, 0, stream>>>(deg, bofs, offs, dcur, perm, N);
    k_fillr<<<(E / 4 + 255) / 256, 256, 0, stream>>>(ei, rank, offs, csr, E);

    // Layer 1: BM=64, K=128, F=64, A-stride 132
    k_gemm<64, IN_CH, HID, 132><<<(N + 63) / 64, 256, 0, stream>>>(x, W1, dinv, h1p, N);
    k_gather1<<<(((N + 3) / 4) * 64 + 255) / 256, 256, 0, stream>>>(h1p, offs, csr, dinv, perm, b1, g1, be1, rm1, rv1, hact, N);
    // Layer 2: BM=128, K=64, F=32, A-stride 68
    k_gemm<128, HID, HID2, 68><<<(N + 127) / 128, 256, 0, stream>>>(hact, W2, dinv, h2p, N);
    k_gather2<<<(((N + 7) / 8) * 64 + 255) / 256, 256, 0, stream>>>(h2p, offs, csr, dinv, perm, b2, g2, be2, rm2, rv2, fcW, fcb, out, N);
}

// Round 8
// 235.692 us; speedup vs baseline: 1.5540x; 1.5540x over previous
//
#include <hip/hip_runtime.h>

#define N_NODES 50000
#define N_EDGES 800000
#define IN_CH 128
#define HID 64
#define HID2 32
#define BN_EPS 1e-5f

// ---------- degree + per-edge rank (one atomic pass, coalesced rank store) ----------
__global__ __launch_bounds__(256) void k_degrank(const int* __restrict__ ei, int* __restrict__ deg,
                                                 int* __restrict__ rank, int E) {
    int t = blockIdx.x * 256 + threadIdx.x;
    int e = t * 4;
    if (e >= E) return;
    int4 c4 = *(const int4*)(ei + E + e);
    int4 rk;
    rk.x = atomicAdd(&deg[c4.x], 1);
    rk.y = atomicAdd(&deg[c4.y], 1);
    rk.z = atomicAdd(&deg[c4.z], 1);
    rk.w = atomicAdd(&deg[c4.w], 1);
    *(int4*)(rank + e) = rk;
}

// ---------- scan stage 1: block sums + dinv + histogram + per-node local rank ----------
// lrank[i] = rank of node i within (its block, its degree bin)   [LDS atomic]
// bbase[block][bin] = base of this block's slice within the bin  [1 global atomic per block-bin]
__global__ __launch_bounds__(256) void k_scan1(const int* __restrict__ deg, int* __restrict__ bsum,
                                               float* __restrict__ dinv, int* __restrict__ dhist,
                                               int* __restrict__ lrank, int* __restrict__ bbase, int N) {
    __shared__ int s[256];
    __shared__ int hist[256];
    int i = blockIdx.x * 256 + threadIdx.x, t = threadIdx.x;
    int d = (i < N) ? deg[i] : 0;
    if (i < N) dinv[i] = rsqrtf((float)d + 1.0f);  // +1 = self loop
    hist[t] = 0;
    s[t] = d;
    __syncthreads();
    if (i < N) lrank[i] = atomicAdd(&hist[d < 255 ? d : 255], 1);
    for (int off = 128; off > 0; off >>= 1) {
        if (t < off) s[t] += s[t + off];
        __syncthreads();
    }
    if (t == 0) bsum[blockIdx.x] = s[0];
    __syncthreads();
    int gb = 0;
    if (hist[t] > 0) gb = atomicAdd(&dhist[t], hist[t]);
    bbase[blockIdx.x * 256 + t] = gb;
}

// ---------- scan stage 2 (single block): scan block sums AND bin totals ----------
__global__ __launch_bounds__(256) void k_scan2(const int* __restrict__ bsum, int* __restrict__ bofs,
                                               int* __restrict__ offs, const int* __restrict__ dhist,
                                               int* __restrict__ dstart, int NB, int N) {
    __shared__ int s[256];
    int t = threadIdx.x;
    int v = (t < NB) ? bsum[t] : 0;
    s[t] = v; __syncthreads();
    for (int off = 1; off < 256; off <<= 1) {
        int u = (t >= off) ? s[t - off] : 0;
        __syncthreads(); s[t] += u; __syncthreads();
    }
    if (t < NB) bofs[t] = s[t] - v;          // exclusive
    if (t == NB - 1) offs[N] = s[t];         // total == E
    __syncthreads();
    int h = dhist[t];
    s[t] = h; __syncthreads();
    for (int off = 1; off < 256; off <<= 1) {
        int u = (t >= off) ? s[t - off] : 0;
        __syncthreads(); s[t] += u; __syncthreads();
    }
    dstart[t] = s[t] - h;                    // exclusive bin start
}

// ---------- scan stage 3: node CSR offsets + atomic-free perm placement ----------
__global__ __launch_bounds__(256) void k_scan3(const int* __restrict__ deg, const int* __restrict__ bofs,
                                               int* __restrict__ offs, const int* __restrict__ dstart,
                                               const int* __restrict__ bbase, const int* __restrict__ lrank,
                                               int* __restrict__ perm, int N) {
    __shared__ int s[256];
    int i = blockIdx.x * 256 + threadIdx.x, t = threadIdx.x;
    int v = (i < N) ? deg[i] : 0;
    s[t] = v; __syncthreads();
    for (int off = 1; off < 256; off <<= 1) {
        int u = (t >= off) ? s[t - off] : 0;
        __syncthreads(); s[t] += u; __syncthreads();
    }
    if (i < N) {
        offs[i] = bofs[blockIdx.x] + s[t] - v;
        int bin = v < 255 ? v : 255;
        perm[dstart[bin] + bbase[blockIdx.x * 256 + bin] + lrank[i]] = i;
    }
}

// ---------- CSR fill, atomic-free: csr[offs[c]+rank[e]] = row (ushort: N<65536) ----------
__global__ __launch_bounds__(256) void k_fillr(const int* __restrict__ ei, const int* __restrict__ rank,
                                               const int* __restrict__ offs, unsigned short* __restrict__ csr, int E) {
    int t = blockIdx.x * 256 + threadIdx.x;
    int e = t * 4;
    if (e >= E) return;
    int4 r4 = *(const int4*)(ei + e);
    int4 c4 = *(const int4*)(ei + E + e);
    int4 k4 = *(const int4*)(rank + e);
    csr[offs[c4.x] + k4.x] = (unsigned short)r4.x;
    csr[offs[c4.y] + k4.y] = (unsigned short)r4.y;
    csr[offs[c4.z] + k4.z] = (unsigned short)r4.z;
    csr[offs[c4.w] + k4.w] = (unsigned short)r4.w;
}

// ---------- LDS-tiled GEMM: outp[n][f] = dinv[n] * sum_k in[n][k]*W[k][f] ----------
template <int BM, int KD, int FD, int AS>
__global__ __launch_bounds__(256) void k_gemm(const float* __restrict__ in, const float* __restrict__ W,
                                              const float* __restrict__ dinv, float* __restrict__ outp, int N) {
    __shared__ float As[BM * AS];
    __shared__ float Ws[KD * FD];
    int tid = threadIdx.x;
    int n0 = blockIdx.x * BM;
    const int TOT4 = BM * KD / 4;
    const int K4 = KD / 4;
#pragma unroll
    for (int idx = tid; idx < TOT4; idx += 256) {
        int r = idx / K4, c = idx % K4;
        int n = n0 + r; if (n > N - 1) n = N - 1;
        float4 v = *(const float4*)(in + (size_t)n * KD + c * 4);
        *(float4*)(As + r * AS + c * 4) = v;
    }
    const int WT4 = KD * FD / 4;
#pragma unroll
    for (int idx = tid; idx < WT4; idx += 256) {
        *(float4*)(Ws + idx * 4) = *(const float4*)(W + idx * 4);
    }
    __syncthreads();
    const int NFG = FD / 4;
    int tn = tid % NFG, tm = tid / NFG;
    int na = tm * 4, fb = tn * 4;
    float acc[4][4] = {};
#pragma unroll 4
    for (int k = 0; k < KD; k += 4) {
        float4 a[4], b[4];
#pragma unroll
        for (int i = 0; i < 4; ++i) a[i] = *(const float4*)(As + (na + i) * AS + k);
#pragma unroll
        for (int j = 0; j < 4; ++j) b[j] = *(const float4*)(Ws + (k + j) * FD + fb);
#pragma unroll
        for (int i = 0; i < 4; ++i) {
            acc[i][0] = fmaf(a[i].x, b[0].x, acc[i][0]);
            acc[i][1] = fmaf(a[i].x, b[0].y, acc[i][1]);
            acc[i][2] = fmaf(a[i].x, b[0].z, acc[i][2]);
            acc[i][3] = fmaf(a[i].x, b[0].w, acc[i][3]);
            acc[i][0] = fmaf(a[i].y, b[1].x, acc[i][0]);
            acc[i][1] = fmaf(a[i].y, b[1].y, acc[i][1]);
            acc[i][2] = fmaf(a[i].y, b[1].z, acc[i][2]);
            acc[i][3] = fmaf(a[i].y, b[1].w, acc[i][3]);
            acc[i][0] = fmaf(a[i].z, b[2].x, acc[i][0]);
            acc[i][1] = fmaf(a[i].z, b[2].y, acc[i][1]);
            acc[i][2] = fmaf(a[i].z, b[2].z, acc[i][2]);
            acc[i][3] = fmaf(a[i].z, b[2].w, acc[i][3]);
            acc[i][0] = fmaf(a[i].w, b[3].x, acc[i][0]);
            acc[i][1] = fmaf(a[i].w, b[3].y, acc[i][1]);
            acc[i][2] = fmaf(a[i].w, b[3].z, acc[i][2]);
            acc[i][3] = fmaf(a[i].w, b[3].w, acc[i][3]);
        }
    }
#pragma unroll
    for (int i = 0; i < 4; ++i) {
        int n = n0 + na + i;
        if (n < N) {
            float dn = dinv[n];
            float4 o = make_float4(acc[i][0] * dn, acc[i][1] * dn, acc[i][2] * dn, acc[i][3] * dn);
            *(float4*)(outp + (size_t)n * FD + fb) = o;
        }
    }
}

// ---------- gather layer 1: 4 nodes/wave via degree-sorted perm, lane = 4 feats ----------
__global__ __launch_bounds__(256) void k_gather1(const float* __restrict__ h1p, const int* __restrict__ offs,
                                                 const unsigned short* __restrict__ csr, const float* __restrict__ dinv,
                                                 const int* __restrict__ perm,
                                                 const float* __restrict__ b1, const float* __restrict__ g1,
                                                 const float* __restrict__ be1, const float* __restrict__ rm1,
                                                 const float* __restrict__ rv1, float* __restrict__ hact, int N) {
    int wid = (blockIdx.x * 256 + threadIdx.x) >> 6;
    int lane = threadIdx.x & 63;
    int sub = lane >> 4;              // node slot 0..3
    int l16 = lane & 15;
    int fl = l16 << 2;                // feature base
    int pidx = wid * 4 + sub;
    if (pidx > N - 1) pidx = N - 1;   // duplicate work, benign (same value rewritten)
    int nd = perm[pidx];
    int start = offs[nd], end = offs[nd + 1];
    float4 acc = *(const float4*)(h1p + ((size_t)nd << 6) + fl);   // self loop
    int sb = sub << 4;
    for (int j = start; j < end; j += 16) {
        int rid = (j + l16 < end) ? (int)csr[j + l16] : 0;
        int cnt = end - j; if (cnt > 16) cnt = 16;
        int t = 0;
        for (; t + 7 < cnt; t += 8) {
            int r0 = __shfl(rid, sb + t + 0, 64), r1 = __shfl(rid, sb + t + 1, 64);
            int r2 = __shfl(rid, sb + t + 2, 64), r3 = __shfl(rid, sb + t + 3, 64);
            int r4 = __shfl(rid, sb + t + 4, 64), r5 = __shfl(rid, sb + t + 5, 64);
            int r6 = __shfl(rid, sb + t + 6, 64), r7 = __shfl(rid, sb + t + 7, 64);
            float4 v0 = *(const float4*)(h1p + ((size_t)r0 << 6) + fl);
            float4 v1 = *(const float4*)(h1p + ((size_t)r1 << 6) + fl);
            float4 v2 = *(const float4*)(h1p + ((size_t)r2 << 6) + fl);
            float4 v3 = *(const float4*)(h1p + ((size_t)r3 << 6) + fl);
            float4 v4 = *(const float4*)(h1p + ((size_t)r4 << 6) + fl);
            float4 v5 = *(const float4*)(h1p + ((size_t)r5 << 6) + fl);
            float4 v6 = *(const float4*)(h1p + ((size_t)r6 << 6) + fl);
            float4 v7 = *(const float4*)(h1p + ((size_t)r7 << 6) + fl);
            acc.x += ((v0.x + v1.x) + (v2.x + v3.x)) + ((v4.x + v5.x) + (v6.x + v7.x));
            acc.y += ((v0.y + v1.y) + (v2.y + v3.y)) + ((v4.y + v5.y) + (v6.y + v7.y));
            acc.z += ((v0.z + v1.z) + (v2.z + v3.z)) + ((v4.z + v5.z) + (v6.z + v7.z));
            acc.w += ((v0.w + v1.w) + (v2.w + v3.w)) + ((v4.w + v5.w) + (v6.w + v7.w));
        }
        for (; t < cnt; ++t) {
            int r = __shfl(rid, sb + t, 64);
            float4 v = *(const float4*)(h1p + ((size_t)r << 6) + fl);
            acc.x += v.x; acc.y += v.y; acc.z += v.z; acc.w += v.w;
        }
    }
    float dn = dinv[nd];
    float4 bb = *(const float4*)(b1 + fl);
    float4 gg = *(const float4*)(g1 + fl);
    float4 ee = *(const float4*)(be1 + fl);
    float4 mm = *(const float4*)(rm1 + fl);
    float4 vv = *(const float4*)(rv1 + fl);
    float4 o;
    o.x = fmaxf((dn * acc.x + bb.x - mm.x) * (gg.x * rsqrtf(vv.x + BN_EPS)) + ee.x, 0.f);
    o.y = fmaxf((dn * acc.y + bb.y - mm.y) * (gg.y * rsqrtf(vv.y + BN_EPS)) + ee.y, 0.f);
    o.z = fmaxf((dn * acc.z + bb.z - mm.z) * (gg.z * rsqrtf(vv.z + BN_EPS)) + ee.z, 0.f);
    o.w = fmaxf((dn * acc.w + bb.w - mm.w) * (gg.w * rsqrtf(vv.w + BN_EPS)) + ee.w, 0.f);
    *(float4*)(hact + ((size_t)nd << 6) + fl) = o;
}

// ---------- gather layer 2: 8 nodes/wave via perm, lane = 4 feats + fused FC ----------
__global__ __launch_bounds__(256) void k_gather2(const float* __restrict__ h2p, const int* __restrict__ offs,
                                                 const unsigned short* __restrict__ csr, const float* __restrict__ dinv,
                                                 const int* __restrict__ perm,
                                                 const float* __restrict__ b2, const float* __restrict__ g2,
                                                 const float* __restrict__ be2, const float* __restrict__ rm2,
                                                 const float* __restrict__ rv2, const float* __restrict__ fcW,
                                                 const float* __restrict__ fcb, float* __restrict__ out, int N) {
    int wid = (blockIdx.x * 256 + threadIdx.x) >> 6;
    int lane = threadIdx.x & 63;
    int sub = lane >> 3;              // node slot 0..7
    int l8 = lane & 7;
    int fl = l8 << 2;                 // feature base 0..28
    int pidx = wid * 8 + sub;
    if (pidx > N - 1) pidx = N - 1;
    int nd = perm[pidx];
    int start = offs[nd], end = offs[nd + 1];
    float4 acc = *(const float4*)(h2p + ((size_t)nd << 5) + fl);   // self loop
    int sb = sub << 3;
    for (int j = start; j < end; j += 8) {
        int rid = (j + l8 < end) ? (int)csr[j + l8] : 0;
        int cnt = end - j; if (cnt > 8) cnt = 8;
        int t = 0;
        for (; t + 3 < cnt; t += 4) {
            int r0 = __shfl(rid, sb + t + 0, 64), r1 = __shfl(rid, sb + t + 1, 64);
            int r2 = __shfl(rid, sb + t + 2, 64), r3 = __shfl(rid, sb + t + 3, 64);
            float4 v0 = *(const float4*)(h2p + ((size_t)r0 << 5) + fl);
            float4 v1 = *(const float4*)(h2p + ((size_t)r1 << 5) + fl);
            float4 v2 = *(const float4*)(h2p + ((size_t)r2 << 5) + fl);
            float4 v3 = *(const float4*)(h2p + ((size_t)r3 << 5) + fl);
            acc.x += (v0.x + v1.x) + (v2.x + v3.x);
            acc.y += (v0.y + v1.y) + (v2.y + v3.y);
            acc.z += (v0.z + v1.z) + (v2.z + v3.z);
            acc.w += (v0.w + v1.w) + (v2.w + v3.w);
        }
        for (; t < cnt; ++t) {
            int r = __shfl(rid, sb + t, 64);
            float4 v = *(const float4*)(h2p + ((size_t)r << 5) + fl);
            acc.x += v.x; acc.y += v.y; acc.z += v.z; acc.w += v.w;
        }
    }
    float dn = dinv[nd];
    float4 bb = *(const float4*)(b2 + fl);
    float4 gg = *(const float4*)(g2 + fl);
    float4 ee = *(const float4*)(be2 + fl);
    float4 mm = *(const float4*)(rm2 + fl);
    float4 vv = *(const float4*)(rv2 + fl);
    float4 ww = *(const float4*)(fcW + fl);
    float s;
    s  = fmaxf((dn * acc.x + bb.x - mm.x) * (gg.x * rsqrtf(vv.x + BN_EPS)) + ee.x, 0.f) * ww.x;
    s += fmaxf((dn * acc.y + bb.y - mm.y) * (gg.y * rsqrtf(vv.y + BN_EPS)) + ee.y, 0.f) * ww.y;
    s += fmaxf((dn * acc.z + bb.z - mm.z) * (gg.z * rsqrtf(vv.z + BN_EPS)) + ee.z, 0.f) * ww.z;
    s += fmaxf((dn * acc.w + bb.w - mm.w) * (gg.w * rsqrtf(vv.w + BN_EPS)) + ee.w, 0.f) * ww.w;
    s += __shfl_down(s, 4, 8);
    s += __shfl_down(s, 2, 8);
    s += __shfl_down(s, 1, 8);
    if (l8 == 0) out[nd] = s + fcb[0];
}

extern "C" void kernel_launch(void* const* d_in, const int* in_sizes, int n_in,
                              void* d_out, int out_size, void* d_ws, size_t ws_size,
                              hipStream_t stream) {
    const float* x   = (const float*)d_in[0];
    const int*   ei  = (const int*)d_in[1];
    const float* W1  = (const float*)d_in[2];
    const float* b1  = (const float*)d_in[3];
    const float* W2  = (const float*)d_in[4];
    const float* b2  = (const float*)d_in[5];
    const float* fcW = (const float*)d_in[6];
    const float* fcb = (const float*)d_in[7];
    const float* g1  = (const float*)d_in[8];
    const float* be1 = (const float*)d_in[9];
    const float* rm1 = (const float*)d_in[10];
    const float* rv1 = (const float*)d_in[11];
    const float* g2  = (const float*)d_in[12];
    const float* be2 = (const float*)d_in[13];
    const float* rm2 = (const float*)d_in[14];
    const float* rv2 = (const float*)d_in[15];
    float* out = (float*)d_out;

    const int N = N_NODES, E = N_EDGES;
    const int NB = (N + 255) / 256;          // 196 scan blocks

    char* base = (char*)d_ws;
    int*            deg   = (int*)(base);                      // N ints
    int*            offs  = (int*)(base + 200704);             // N+1 ints
    float*          dinv  = (float*)(base + 401408);           // N floats
    int*            perm  = (int*)(base + 602112);             // N ints
    int*            lrank = (int*)(base + 802816);             // N ints
    int*            bbase = (int*)(base + 1003520);            // NB*256 = 50176 ints (200704 B)
    int*            bsum  = (int*)(base + 1204224);            // 256
    int*            bofs  = (int*)(base + 1205248);            // 256
    int*            dhist = (int*)(base + 1206272);            // 256
    int*            dstart= (int*)(base + 1207296);            // 256
    int*            rank  = (int*)(base + 1208320);            // E ints (3.2 MB)
    unsigned short* csr   = (unsigned short*)(base + 4408320); // E ushort (1.6 MB)
    float*          h1p   = (float*)(base + 6008320);          // N*64 (12.8 MB)
    float*          hact  = (float*)(base + 18808320);         // N*64 (12.8 MB)
    float*          h2p   = h1p;   // h1p dead after gather1

    hipMemsetAsync(deg, 0, (size_t)N * sizeof(int), stream);
    hipMemsetAsync(dhist, 0, 256 * sizeof(int), stream);

    k_degrank<<<(E / 4 + 255) / 256, 256, 0, stream>>>(ei, deg, rank, E);
    k_scan1<<<NB, 256, 0, stream>>>(deg, bsum, dinv, dhist, lrank, bbase, N);
    k_scan2<<<1, 256, 0, stream>>>(bsum, bofs, offs, dhist, dstart, NB, N);
    k_scan3<<<NB, 256, 0, stream>>>(deg, bofs, offs, dstart, bbase, lrank, perm, N);
    k_fillr<<<(E / 4 + 255) / 256, 256, 0, stream>>>(ei, rank, offs, csr, E);

    // Layer 1: BM=64, K=128, F=64, A-stride 132
    k_gemm<64, IN_CH, HID, 132><<<(N + 63) / 64, 256, 0, stream>>>(x, W1, dinv, h1p, N);
    k_gather1<<<(((N + 3) / 4) * 64 + 255) / 256, 256, 0, stream>>>(h1p, offs, csr, dinv, perm, b1, g1, be1, rm1, rv1, hact, N);
    // Layer 2: BM=128, K=64, F=32, A-stride 68
    k_gemm<128, HID, HID2, 68><<<(N + 127) / 128, 256, 0, stream>>>(hact, W2, dinv, h2p, N);
    k_gather2<<<(((N + 7) / 8) * 64 + 255) / 256, 256, 0, stream>>>(h2p, offs, csr, dinv, perm, b2, g2, be2, rm2, rv2, fcW, fcb, out, N);
}

// Round 9
// 226.726 us; speedup vs baseline: 1.6154x; 1.0395x over previous
//
#include <hip/hip_runtime.h>

#define N_NODES 50000
#define N_EDGES 800000
#define IN_CH 128
#define HID 64
#define HID2 32
#define BN_EPS 1e-5f

// ---------- degree + per-edge rank (one atomic pass, coalesced ushort rank store) ----------
__global__ __launch_bounds__(256) void k_degrank(const int* __restrict__ ei, int* __restrict__ deg,
                                                 unsigned short* __restrict__ rank, int E) {
    int t = blockIdx.x * 256 + threadIdx.x;
    int e = t * 4;
    if (e >= E) return;
    int4 c4 = *(const int4*)(ei + E + e);
    ushort4 rk;
    rk.x = (unsigned short)atomicAdd(&deg[c4.x], 1);
    rk.y = (unsigned short)atomicAdd(&deg[c4.y], 1);
    rk.z = (unsigned short)atomicAdd(&deg[c4.z], 1);
    rk.w = (unsigned short)atomicAdd(&deg[c4.w], 1);
    *(ushort4*)(rank + e) = rk;
}

// ---------- scan stage 1: block sums + dinv ----------
__global__ __launch_bounds__(256) void k_scan1(const int* __restrict__ deg, int* __restrict__ bsum,
                                               float* __restrict__ dinv, int N) {
    __shared__ int s[256];
    int i = blockIdx.x * 256 + threadIdx.x, t = threadIdx.x;
    int d = (i < N) ? deg[i] : 0;
    if (i < N) dinv[i] = rsqrtf((float)d + 1.0f);  // +1 = self loop
    s[t] = d;
    __syncthreads();
    for (int off = 128; off > 0; off >>= 1) {
        if (t < off) s[t] += s[t + off];
        __syncthreads();
    }
    if (t == 0) bsum[blockIdx.x] = s[0];
}

// ---------- scan stage 2 (fused): each block reduces its own prefix of bsum, then local scan ----------
__global__ __launch_bounds__(256) void k_scan3(const int* __restrict__ deg, const int* __restrict__ bsum,
                                               int* __restrict__ offs, int N, int NB) {
    __shared__ int s[256];
    __shared__ int p[256];
    int i = blockIdx.x * 256 + threadIdx.x, t = threadIdx.x;
    int v = (i < N) ? deg[i] : 0;
    p[t] = (t < blockIdx.x && t < NB) ? bsum[t] : 0;   // NB<=256
    s[t] = v;
    __syncthreads();
    for (int off = 128; off > 0; off >>= 1) {
        if (t < off) p[t] += p[t + off];
        __syncthreads();
    }
    int pref = p[0];
    for (int off = 1; off < 256; off <<= 1) {
        int u = (t >= off) ? s[t - off] : 0;
        __syncthreads(); s[t] += u; __syncthreads();
    }
    if (i < N) offs[i] = pref + s[t] - v;              // exclusive
    if (i == N - 1) offs[N] = pref + s[t];             // total == E
}

// ---------- CSR fill, atomic-free: csr[offs[c]+rank[e]] = row (ushort: N<65536) ----------
__global__ __launch_bounds__(256) void k_fillr(const int* __restrict__ ei, const unsigned short* __restrict__ rank,
                                               const int* __restrict__ offs, unsigned short* __restrict__ csr, int E) {
    int t = blockIdx.x * 256 + threadIdx.x;
    int e = t * 4;
    if (e >= E) return;
    int4 r4 = *(const int4*)(ei + e);
    int4 c4 = *(const int4*)(ei + E + e);
    ushort4 k4 = *(const ushort4*)(rank + e);
    csr[offs[c4.x] + k4.x] = (unsigned short)r4.x;
    csr[offs[c4.y] + k4.y] = (unsigned short)r4.y;
    csr[offs[c4.z] + k4.z] = (unsigned short)r4.z;
    csr[offs[c4.w] + k4.w] = (unsigned short)r4.w;
}

// ---------- LDS-tiled GEMM: outp[n][f] = dinv[n] * sum_k in[n][k]*W[k][f] ----------
template <int BM, int KD, int FD, int AS>
__global__ __launch_bounds__(256) void k_gemm(const float* __restrict__ in, const float* __restrict__ W,
                                              const float* __restrict__ dinv, float* __restrict__ outp, int N) {
    __shared__ float As[BM * AS];
    __shared__ float Ws[KD * FD];
    int tid = threadIdx.x;
    int n0 = blockIdx.x * BM;
    const int TOT4 = BM * KD / 4;
    const int K4 = KD / 4;
#pragma unroll
    for (int idx = tid; idx < TOT4; idx += 256) {
        int r = idx / K4, c = idx % K4;
        int n = n0 + r; if (n > N - 1) n = N - 1;
        float4 v = *(const float4*)(in + (size_t)n * KD + c * 4);
        *(float4*)(As + r * AS + c * 4) = v;
    }
    const int WT4 = KD * FD / 4;
#pragma unroll
    for (int idx = tid; idx < WT4; idx += 256) {
        *(float4*)(Ws + idx * 4) = *(const float4*)(W + idx * 4);
    }
    __syncthreads();
    const int NFG = FD / 4;
    int tn = tid % NFG, tm = tid / NFG;
    int na = tm * 4, fb = tn * 4;
    float acc[4][4] = {};
#pragma unroll 4
    for (int k = 0; k < KD; k += 4) {
        float4 a[4], b[4];
#pragma unroll
        for (int i = 0; i < 4; ++i) a[i] = *(const float4*)(As + (na + i) * AS + k);
#pragma unroll
        for (int j = 0; j < 4; ++j) b[j] = *(const float4*)(Ws + (k + j) * FD + fb);
#pragma unroll
        for (int i = 0; i < 4; ++i) {
            acc[i][0] = fmaf(a[i].x, b[0].x, acc[i][0]);
            acc[i][1] = fmaf(a[i].x, b[0].y, acc[i][1]);
            acc[i][2] = fmaf(a[i].x, b[0].z, acc[i][2]);
            acc[i][3] = fmaf(a[i].x, b[0].w, acc[i][3]);
            acc[i][0] = fmaf(a[i].y, b[1].x, acc[i][0]);
            acc[i][1] = fmaf(a[i].y, b[1].y, acc[i][1]);
            acc[i][2] = fmaf(a[i].y, b[1].z, acc[i][2]);
            acc[i][3] = fmaf(a[i].y, b[1].w, acc[i][3]);
            acc[i][0] = fmaf(a[i].z, b[2].x, acc[i][0]);
            acc[i][1] = fmaf(a[i].z, b[2].y, acc[i][1]);
            acc[i][2] = fmaf(a[i].z, b[2].z, acc[i][2]);
            acc[i][3] = fmaf(a[i].z, b[2].w, acc[i][3]);
            acc[i][0] = fmaf(a[i].w, b[3].x, acc[i][0]);
            acc[i][1] = fmaf(a[i].w, b[3].y, acc[i][1]);
            acc[i][2] = fmaf(a[i].w, b[3].z, acc[i][2]);
            acc[i][3] = fmaf(a[i].w, b[3].w, acc[i][3]);
        }
    }
#pragma unroll
    for (int i = 0; i < 4; ++i) {
        int n = n0 + na + i;
        if (n < N) {
            float dn = dinv[n];
            float4 o = make_float4(acc[i][0] * dn, acc[i][1] * dn, acc[i][2] * dn, acc[i][3] * dn);
            *(float4*)(outp + (size_t)n * FD + fb) = o;
        }
    }
}

// ---------- gather layer 1: 4 nodes/wave (natural order), lane = 4 feats ----------
__global__ __launch_bounds__(256) void k_gather1(const float* __restrict__ h1p, const int* __restrict__ offs,
                                                 const unsigned short* __restrict__ csr, const float* __restrict__ dinv,
                                                 const float* __restrict__ b1, const float* __restrict__ g1,
                                                 const float* __restrict__ be1, const float* __restrict__ rm1,
                                                 const float* __restrict__ rv1, float* __restrict__ hact, int N) {
    int wid = (blockIdx.x * 256 + threadIdx.x) >> 6;
    int lane = threadIdx.x & 63;
    int sub = lane >> 4;              // node slot 0..3
    int l16 = lane & 15;
    int fl = l16 << 2;                // feature base
    int nd = wid * 4 + sub;           // grid sized exactly: nd < N always (N%4==0)
    int start = offs[nd], end = offs[nd + 1];
    float4 acc = *(const float4*)(h1p + ((size_t)nd << 6) + fl);   // self loop
    int sb = sub << 4;
    for (int j = start; j < end; j += 16) {
        int rid = (j + l16 < end) ? (int)csr[j + l16] : 0;
        int cnt = end - j; if (cnt > 16) cnt = 16;
        int t = 0;
        for (; t + 7 < cnt; t += 8) {
            int r0 = __shfl(rid, sb + t + 0, 64), r1 = __shfl(rid, sb + t + 1, 64);
            int r2 = __shfl(rid, sb + t + 2, 64), r3 = __shfl(rid, sb + t + 3, 64);
            int r4 = __shfl(rid, sb + t + 4, 64), r5 = __shfl(rid, sb + t + 5, 64);
            int r6 = __shfl(rid, sb + t + 6, 64), r7 = __shfl(rid, sb + t + 7, 64);
            float4 v0 = *(const float4*)(h1p + ((size_t)r0 << 6) + fl);
            float4 v1 = *(const float4*)(h1p + ((size_t)r1 << 6) + fl);
            float4 v2 = *(const float4*)(h1p + ((size_t)r2 << 6) + fl);
            float4 v3 = *(const float4*)(h1p + ((size_t)r3 << 6) + fl);
            float4 v4 = *(const float4*)(h1p + ((size_t)r4 << 6) + fl);
            float4 v5 = *(const float4*)(h1p + ((size_t)r5 << 6) + fl);
            float4 v6 = *(const float4*)(h1p + ((size_t)r6 << 6) + fl);
            float4 v7 = *(const float4*)(h1p + ((size_t)r7 << 6) + fl);
            acc.x += ((v0.x + v1.x) + (v2.x + v3.x)) + ((v4.x + v5.x) + (v6.x + v7.x));
            acc.y += ((v0.y + v1.y) + (v2.y + v3.y)) + ((v4.y + v5.y) + (v6.y + v7.y));
            acc.z += ((v0.z + v1.z) + (v2.z + v3.z)) + ((v4.z + v5.z) + (v6.z + v7.z));
            acc.w += ((v0.w + v1.w) + (v2.w + v3.w)) + ((v4.w + v5.w) + (v6.w + v7.w));
        }
        for (; t < cnt; ++t) {
            int r = __shfl(rid, sb + t, 64);
            float4 v = *(const float4*)(h1p + ((size_t)r << 6) + fl);
            acc.x += v.x; acc.y += v.y; acc.z += v.z; acc.w += v.w;
        }
    }
    float dn = dinv[nd];
    float4 bb = *(const float4*)(b1 + fl);
    float4 gg = *(const float4*)(g1 + fl);
    float4 ee = *(const float4*)(be1 + fl);
    float4 mm = *(const float4*)(rm1 + fl);
    float4 vv = *(const float4*)(rv1 + fl);
    float4 o;
    o.x = fmaxf((dn * acc.x + bb.x - mm.x) * (gg.x * rsqrtf(vv.x + BN_EPS)) + ee.x, 0.f);
    o.y = fmaxf((dn * acc.y + bb.y - mm.y) * (gg.y * rsqrtf(vv.y + BN_EPS)) + ee.y, 0.f);
    o.z = fmaxf((dn * acc.z + bb.z - mm.z) * (gg.z * rsqrtf(vv.z + BN_EPS)) + ee.z, 0.f);
    o.w = fmaxf((dn * acc.w + bb.w - mm.w) * (gg.w * rsqrtf(vv.w + BN_EPS)) + ee.w, 0.f);
    *(float4*)(hact + ((size_t)nd << 6) + fl) = o;
}

// ---------- gather layer 2: 8 nodes/wave (natural order), lane = 4 feats + fused FC ----------
__global__ __launch_bounds__(256) void k_gather2(const float* __restrict__ h2p, const int* __restrict__ offs,
                                                 const unsigned short* __restrict__ csr, const float* __restrict__ dinv,
                                                 const float* __restrict__ b2, const float* __restrict__ g2,
                                                 const float* __restrict__ be2, const float* __restrict__ rm2,
                                                 const float* __restrict__ rv2, const float* __restrict__ fcW,
                                                 const float* __restrict__ fcb, float* __restrict__ out, int N) {
    int wid = (blockIdx.x * 256 + threadIdx.x) >> 6;
    int lane = threadIdx.x & 63;
    int sub = lane >> 3;              // node slot 0..7
    int l8 = lane & 7;
    int fl = l8 << 2;                 // feature base 0..28
    int nd = wid * 8 + sub;
    bool ok = nd < N;
    if (!ok) nd = N - 1;
    int start = offs[nd], end = offs[nd + 1];
    float4 acc = *(const float4*)(h2p + ((size_t)nd << 5) + fl);   // self loop
    int sb = sub << 3;
    for (int j = start; j < end; j += 8) {
        int rid = (j + l8 < end) ? (int)csr[j + l8] : 0;
        int cnt = end - j; if (cnt > 8) cnt = 8;
        int t = 0;
        for (; t + 7 < cnt; t += 8) {
            int r0 = __shfl(rid, sb + 0, 64), r1 = __shfl(rid, sb + 1, 64);
            int r2 = __shfl(rid, sb + 2, 64), r3 = __shfl(rid, sb + 3, 64);
            int r4 = __shfl(rid, sb + 4, 64), r5 = __shfl(rid, sb + 5, 64);
            int r6 = __shfl(rid, sb + 6, 64), r7 = __shfl(rid, sb + 7, 64);
            float4 v0 = *(const float4*)(h2p + ((size_t)r0 << 5) + fl);
            float4 v1 = *(const float4*)(h2p + ((size_t)r1 << 5) + fl);
            float4 v2 = *(const float4*)(h2p + ((size_t)r2 << 5) + fl);
            float4 v3 = *(const float4*)(h2p + ((size_t)r3 << 5) + fl);
            float4 v4 = *(const float4*)(h2p + ((size_t)r4 << 5) + fl);
            float4 v5 = *(const float4*)(h2p + ((size_t)r5 << 5) + fl);
            float4 v6 = *(const float4*)(h2p + ((size_t)r6 << 5) + fl);
            float4 v7 = *(const float4*)(h2p + ((size_t)r7 << 5) + fl);
            acc.x += ((v0.x + v1.x) + (v2.x + v3.x)) + ((v4.x + v5.x) + (v6.x + v7.x));
            acc.y += ((v0.y + v1.y) + (v2.y + v3.y)) + ((v4.y + v5.y) + (v6.y + v7.y));
            acc.z += ((v0.z + v1.z) + (v2.z + v3.z)) + ((v4.z + v5.z) + (v6.z + v7.z));
            acc.w += ((v0.w + v1.w) + (v2.w + v3.w)) + ((v4.w + v5.w) + (v6.w + v7.w));
        }
        for (; t < cnt; ++t) {
            int r = __shfl(rid, sb + t, 64);
            float4 v = *(const float4*)(h2p + ((size_t)r << 5) + fl);
            acc.x += v.x; acc.y += v.y; acc.z += v.z; acc.w += v.w;
        }
    }
    float dn = dinv[nd];
    float4 bb = *(const float4*)(b2 + fl);
    float4 gg = *(const float4*)(g2 + fl);
    float4 ee = *(const float4*)(be2 + fl);
    float4 mm = *(const float4*)(rm2 + fl);
    float4 vv = *(const float4*)(rv2 + fl);
    float4 ww = *(const float4*)(fcW + fl);
    float s;
    s  = fmaxf((dn * acc.x + bb.x - mm.x) * (gg.x * rsqrtf(vv.x + BN_EPS)) + ee.x, 0.f) * ww.x;
    s += fmaxf((dn * acc.y + bb.y - mm.y) * (gg.y * rsqrtf(vv.y + BN_EPS)) + ee.y, 0.f) * ww.y;
    s += fmaxf((dn * acc.z + bb.z - mm.z) * (gg.z * rsqrtf(vv.z + BN_EPS)) + ee.z, 0.f) * ww.z;
    s += fmaxf((dn * acc.w + bb.w - mm.w) * (gg.w * rsqrtf(vv.w + BN_EPS)) + ee.w, 0.f) * ww.w;
    s += __shfl_down(s, 4, 8);
    s += __shfl_down(s, 2, 8);
    s += __shfl_down(s, 1, 8);
    if (ok && l8 == 0) out[nd] = s + fcb[0];
}

extern "C" void kernel_launch(void* const* d_in, const int* in_sizes, int n_in,
                              void* d_out, int out_size, void* d_ws, size_t ws_size,
                              hipStream_t stream) {
    const float* x   = (const float*)d_in[0];
    const int*   ei  = (const int*)d_in[1];
    const float* W1  = (const float*)d_in[2];
    const float* b1  = (const float*)d_in[3];
    const float* W2  = (const float*)d_in[4];
    const float* b2  = (const float*)d_in[5];
    const float* fcW = (const float*)d_in[6];
    const float* fcb = (const float*)d_in[7];
    const float* g1  = (const float*)d_in[8];
    const float* be1 = (const float*)d_in[9];
    const float* rm1 = (const float*)d_in[10];
    const float* rv1 = (const float*)d_in[11];
    const float* g2  = (const float*)d_in[12];
    const float* be2 = (const float*)d_in[13];
    const float* rm2 = (const float*)d_in[14];
    const float* rv2 = (const float*)d_in[15];
    float* out = (float*)d_out;

    const int N = N_NODES, E = N_EDGES;
    const int NB = (N + 255) / 256;          // 196 scan blocks

    char* base = (char*)d_ws;
    int*            deg  = (int*)(base);                      // N ints
    int*            offs = (int*)(base + 200704);             // N+1 ints
    float*          dinv = (float*)(base + 401408);           // N floats
    int*            bsum = (int*)(base + 602112);             // 256 ints
    unsigned short* rank = (unsigned short*)(base + 603136);  // E ushort (1.6 MB)
    unsigned short* csr  = (unsigned short*)(base + 2203136); // E ushort (1.6 MB)
    float*          h1p  = (float*)(base + 3803136);          // N*64 (12.8 MB)
    float*          hact = (float*)(base + 16603136);         // N*64 (12.8 MB)
    float*          h2p  = h1p;   // h1p dead after gather1

    hipMemsetAsync(deg, 0, (size_t)N * sizeof(int), stream);

    k_degrank<<<(E / 4 + 255) / 256, 256, 0, stream>>>(ei, deg, rank, E);
    k_scan1<<<NB, 256, 0, stream>>>(deg, bsum, dinv, N);
    k_scan3<<<NB, 256, 0, stream>>>(deg, bsum, offs, N, NB);
    k_fillr<<<(E / 4 + 255) / 256, 256, 0, stream>>>(ei, rank, offs, csr, E);

    // Layer 1: BM=64, K=128, F=64, A-stride 132
    k_gemm<64, IN_CH, HID, 132><<<(N + 63) / 64, 256, 0, stream>>>(x, W1, dinv, h1p, N);
    k_gather1<<<(N / 4) * 64 / 256, 256, 0, stream>>>(h1p, offs, csr, dinv, b1, g1, be1, rm1, rv1, hact, N);
    // Layer 2: BM=128, K=64, F=32, A-stride 68
    k_gemm<128, HID, HID2, 68><<<(N + 127) / 128, 256, 0, stream>>>(hact, W2, dinv, h2p, N);
    k_gather2<<<(((N + 7) / 8) * 64 + 255) / 256, 256, 0, stream>>>(h2p, offs, csr, dinv, b2, g2, be2, rm2, rv2, fcW, fcb, out, N);
}